// Round 1
// baseline (2798.264 us; speedup 1.0000x reference)
//
#include <hip/hip_runtime.h>
#include <hip/hip_bf16.h>

#define N_NODES 100000
#define N_EDGES 3200000
#define HID 64
#define GDIM 32
#define NUM_GRAPHS 16

// ---------- helpers ----------
__device__ __forceinline__ unsigned fkey(float f) {
    unsigned u = __float_as_uint(f);
    return (u & 0x80000000u) ? ~u : (u | 0x80000000u);
}
__device__ __forceinline__ float funkey(unsigned k) {
    unsigned u = (k & 0x80000000u) ? (k ^ 0x80000000u) : ~k;
    return __uint_as_float(u);
}

// ---------- CSR build ----------
__global__ void count_kernel(const int* __restrict__ dst, int* __restrict__ deg, int E) {
    int e = blockIdx.x * blockDim.x + threadIdx.x;
    if (e < E) atomicAdd(&deg[dst[e]], 1);
}

__global__ void scan_kernel(const int* __restrict__ deg, int* __restrict__ rowstart,
                            int* __restrict__ cursor, int N) {
    __shared__ int part[1024];
    int t = threadIdx.x;
    const int CH = (N + 1023) / 1024;
    int lo = t * CH, hi = min(lo + CH, N);
    int s = 0;
    for (int i = lo; i < hi; i++) s += deg[i];
    part[t] = s;
    __syncthreads();
    for (int off = 1; off < 1024; off <<= 1) {
        int v = (t >= off) ? part[t - off] : 0;
        __syncthreads();
        part[t] += v;
        __syncthreads();
    }
    int run = (t == 0) ? 0 : part[t - 1];
    for (int i = lo; i < hi; i++) {
        rowstart[i] = run; cursor[i] = run; run += deg[i];
    }
    if (t == 1023) rowstart[N] = part[1023];
}

__global__ void csrfill_kernel(const int* __restrict__ src, const int* __restrict__ dst,
                               int* __restrict__ cursor, int* __restrict__ csr, int E) {
    int e = blockIdx.x * blockDim.x + threadIdx.x;
    if (e < E) {
        int d = dst[e];
        int pos = atomicAdd(&cursor[d], 1);
        csr[pos] = src[e];
    }
}

// ---------- lin0: y = x @ W + b  (N x 64) ----------
__global__ void lin0_kernel(const float* __restrict__ x, const float* __restrict__ W,
                            const float* __restrict__ b, float* __restrict__ y, int N) {
    __shared__ __align__(16) float Wl[64 * 64];
    __shared__ float bl[64];
    int t = threadIdx.x;
    for (int i = t; i < 64 * 64; i += 256) Wl[i] = W[i];
    if (t < 64) bl[t] = b[t];
    __syncthreads();
    int row = blockIdx.x * 256 + t;
    if (row >= N) return;
    float acc[64];
#pragma unroll
    for (int j = 0; j < 64; j++) acc[j] = bl[j];
    const float4* xr = (const float4*)(x + (size_t)row * 64);
#pragma unroll
    for (int c = 0; c < 16; c++) {
        float4 xv = xr[c];
        float xs[4] = {xv.x, xv.y, xv.z, xv.w};
#pragma unroll
        for (int kk = 0; kk < 4; kk++) {
            int k = c * 4 + kk;
#pragma unroll
            for (int j4 = 0; j4 < 16; j4++) {
                float4 w = *(const float4*)&Wl[k * 64 + j4 * 4];
                acc[j4 * 4 + 0] += xs[kk] * w.x;
                acc[j4 * 4 + 1] += xs[kk] * w.y;
                acc[j4 * 4 + 2] += xs[kk] * w.z;
                acc[j4 * 4 + 3] += xs[kk] * w.w;
            }
        }
    }
    float4* yr = (float4*)(y + (size_t)row * 64);
#pragma unroll
    for (int c = 0; c < 16; c++)
        yr[c] = make_float4(acc[c * 4], acc[c * 4 + 1], acc[c * 4 + 2], acc[c * 4 + 3]);
}

// ---------- mean aggregation: one wave per node, lane = feature ----------
__global__ void agg_kernel(const float* __restrict__ xin, const int* __restrict__ rowstart,
                           const int* __restrict__ csr, float* __restrict__ meanout, int N) {
    int wid = threadIdx.x >> 6, lane = threadIdx.x & 63;
    int node = blockIdx.x * (blockDim.x >> 6) + wid;
    if (node >= N) return;
    int ro = rowstart[node], re = rowstart[node + 1];
    float acc = 0.f;
    for (int base = ro; base < re; base += 64) {
        int rem = re - base;
        int idx = 0;
        if (lane < rem) idx = csr[base + lane];
        int kmax = rem < 64 ? rem : 64;
        for (int k = 0; k < kmax; k++) {
            int s = __shfl(idx, k);
            acc += xin[(size_t)s * 64 + lane];
        }
    }
    int deg = re - ro;
    float inv = 1.0f / (float)(deg > 0 ? deg : 1);
    meanout[(size_t)node * 64 + lane] = acc * inv;
}

// ---------- sage: xout = mean @ LW + lb + xin @ RW ----------
__global__ void sage_kernel(const float* __restrict__ mean, const float* __restrict__ xin,
                            const float* __restrict__ lw, const float* __restrict__ lb,
                            const float* __restrict__ rw, float* __restrict__ xout, int N) {
    __shared__ __align__(16) float LW[64 * 64];
    __shared__ __align__(16) float RW[64 * 64];
    __shared__ float LB[64];
    int t = threadIdx.x;
    for (int i = t; i < 64 * 64; i += 256) { LW[i] = lw[i]; RW[i] = rw[i]; }
    if (t < 64) LB[t] = lb[t];
    __syncthreads();
    int row = blockIdx.x * 256 + t;
    if (row >= N) return;
    float acc[64];
#pragma unroll
    for (int j = 0; j < 64; j++) acc[j] = LB[j];
    const float4* mr = (const float4*)(mean + (size_t)row * 64);
    const float4* xr = (const float4*)(xin + (size_t)row * 64);
#pragma unroll
    for (int c = 0; c < 16; c++) {
        float4 xv = mr[c];
        float xs[4] = {xv.x, xv.y, xv.z, xv.w};
#pragma unroll
        for (int kk = 0; kk < 4; kk++) {
            int k = c * 4 + kk;
#pragma unroll
            for (int j4 = 0; j4 < 16; j4++) {
                float4 w = *(const float4*)&LW[k * 64 + j4 * 4];
                acc[j4 * 4 + 0] += xs[kk] * w.x;
                acc[j4 * 4 + 1] += xs[kk] * w.y;
                acc[j4 * 4 + 2] += xs[kk] * w.z;
                acc[j4 * 4 + 3] += xs[kk] * w.w;
            }
        }
    }
#pragma unroll
    for (int c = 0; c < 16; c++) {
        float4 xv = xr[c];
        float xs[4] = {xv.x, xv.y, xv.z, xv.w};
#pragma unroll
        for (int kk = 0; kk < 4; kk++) {
            int k = c * 4 + kk;
#pragma unroll
            for (int j4 = 0; j4 < 16; j4++) {
                float4 w = *(const float4*)&RW[k * 64 + j4 * 4];
                acc[j4 * 4 + 0] += xs[kk] * w.x;
                acc[j4 * 4 + 1] += xs[kk] * w.y;
                acc[j4 * 4 + 2] += xs[kk] * w.z;
                acc[j4 * 4 + 3] += xs[kk] * w.w;
            }
        }
    }
    float4* yr = (float4*)(xout + (size_t)row * 64);
#pragma unroll
    for (int c = 0; c < 16; c++)
        yr[c] = make_float4(acc[c * 4], acc[c * 4 + 1], acc[c * 4 + 2], acc[c * 4 + 3]);
}

// ---------- head: e0..e2, merge, gate, v; per-graph max of g ----------
__global__ void head_kernel(const float* __restrict__ x0, const float* __restrict__ x1,
                            const float* __restrict__ x2, const int* __restrict__ batch,
                            const float* __restrict__ e0w, const float* __restrict__ e0b,
                            const float* __restrict__ e1w, const float* __restrict__ e1b,
                            const float* __restrict__ e2w, const float* __restrict__ e2b,
                            const float* __restrict__ mw, const float* __restrict__ mb,
                            const float* __restrict__ gw, const float* __restrict__ gbp,
                            const float* __restrict__ vw, const float* __restrict__ vb,
                            float* __restrict__ gout, float* __restrict__ vout,
                            unsigned* __restrict__ mkey, int N) {
    __shared__ __align__(16) float EW[3 * 64 * 32];
    __shared__ __align__(16) float MW[96 * 32];
    __shared__ __align__(16) float VW[32 * 32];
    __shared__ float EB[96], MB[32], GW[32], VB[32];
    __shared__ float GB;
    __shared__ unsigned smax[16];
    int t = threadIdx.x;
    for (int i = t; i < 2048; i += 256) { EW[i] = e0w[i]; EW[2048 + i] = e1w[i]; EW[4096 + i] = e2w[i]; }
    for (int i = t; i < 3072; i += 256) MW[i] = mw[i];
    for (int i = t; i < 1024; i += 256) VW[i] = vw[i];
    if (t < 32) { EB[t] = e0b[t]; EB[32 + t] = e1b[t]; EB[64 + t] = e2b[t];
                  MB[t] = mb[t]; GW[t] = gw[t]; VB[t] = vb[t]; }
    if (t == 0) GB = gbp[0];
    if (t < 16) smax[t] = 0u;
    __syncthreads();
    int node = blockIdx.x * 256 + t;
    if (node < N) {
        float xc[32];
#pragma unroll
        for (int j = 0; j < 32; j++) xc[j] = MB[j];
        const float* px[3] = {x0 + (size_t)node * 64, x1 + (size_t)node * 64, x2 + (size_t)node * 64};
        for (int h = 0; h < 3; h++) {
            float e[32];
#pragma unroll
            for (int j = 0; j < 32; j++) e[j] = EB[h * 32 + j];
            const float4* xr = (const float4*)px[h];
#pragma unroll
            for (int c = 0; c < 16; c++) {
                float4 xv = xr[c];
                float xs[4] = {xv.x, xv.y, xv.z, xv.w};
#pragma unroll
                for (int kk = 0; kk < 4; kk++) {
                    int k = c * 4 + kk;
#pragma unroll
                    for (int j4 = 0; j4 < 8; j4++) {
                        float4 w = *(const float4*)&EW[h * 2048 + k * 32 + j4 * 4];
                        e[j4 * 4 + 0] += xs[kk] * w.x;
                        e[j4 * 4 + 1] += xs[kk] * w.y;
                        e[j4 * 4 + 2] += xs[kk] * w.z;
                        e[j4 * 4 + 3] += xs[kk] * w.w;
                    }
                }
            }
#pragma unroll
            for (int j = 0; j < 32; j++) e[j] = fmaxf(e[j], 0.f);
#pragma unroll
            for (int i = 0; i < 32; i++) {
#pragma unroll
                for (int j4 = 0; j4 < 8; j4++) {
                    float4 w = *(const float4*)&MW[(h * 32 + i) * 32 + j4 * 4];
                    xc[j4 * 4 + 0] += e[i] * w.x;
                    xc[j4 * 4 + 1] += e[i] * w.y;
                    xc[j4 * 4 + 2] += e[i] * w.z;
                    xc[j4 * 4 + 3] += e[i] * w.w;
                }
            }
        }
#pragma unroll
        for (int j = 0; j < 32; j++) xc[j] = fmaxf(xc[j], 0.f);
        float g = GB;
#pragma unroll
        for (int i = 0; i < 32; i++) g += xc[i] * GW[i];
        float vv[32];
#pragma unroll
        for (int j = 0; j < 32; j++) vv[j] = VB[j];
#pragma unroll
        for (int i = 0; i < 32; i++) {
#pragma unroll
            for (int j4 = 0; j4 < 8; j4++) {
                float4 w = *(const float4*)&VW[i * 32 + j4 * 4];
                vv[j4 * 4 + 0] += xc[i] * w.x;
                vv[j4 * 4 + 1] += xc[i] * w.y;
                vv[j4 * 4 + 2] += xc[i] * w.z;
                vv[j4 * 4 + 3] += xc[i] * w.w;
            }
        }
        gout[node] = g;
        float4* vr = (float4*)(vout + (size_t)node * 32);
#pragma unroll
        for (int c = 0; c < 8; c++)
            vr[c] = make_float4(vv[c * 4], vv[c * 4 + 1], vv[c * 4 + 2], vv[c * 4 + 3]);
        int b = batch[node];
        atomicMax(&smax[b], fkey(g));
    }
    __syncthreads();
    if (t < 16) atomicMax(&mkey[t], smax[t]);
}

// ---------- pool: d = seg_sum(e), num = seg_sum(e*v) ----------
__global__ void pool_kernel(const float* __restrict__ g, const float* __restrict__ v,
                            const int* __restrict__ batch, const unsigned* __restrict__ mkey,
                            float* __restrict__ dsum, float* __restrict__ pooled, int N) {
    __shared__ float sd[16];
    __shared__ float sp[16 * 32];
    __shared__ float sm[16];
    int t = threadIdx.x;
    if (t < 16) { sd[t] = 0.f; sm[t] = funkey(mkey[t]); }
    for (int i = t; i < 512; i += 256) sp[i] = 0.f;
    __syncthreads();
    int node = blockIdx.x * 256 + t;
    if (node < N) {
        int b = batch[node];
        float e = __expf(g[node] - sm[b]);
        atomicAdd(&sd[b], e);
        const float4* vr = (const float4*)(v + (size_t)node * 32);
#pragma unroll
        for (int c = 0; c < 8; c++) {
            float4 vv = vr[c];
            atomicAdd(&sp[b * 32 + c * 4 + 0], e * vv.x);
            atomicAdd(&sp[b * 32 + c * 4 + 1], e * vv.y);
            atomicAdd(&sp[b * 32 + c * 4 + 2], e * vv.z);
            atomicAdd(&sp[b * 32 + c * 4 + 3], e * vv.w);
        }
    }
    __syncthreads();
    if (t < 16) atomicAdd(&dsum[t], sd[t]);
    for (int i = t; i < 512; i += 256) atomicAdd(&pooled[i], sp[i]);
}

// ---------- final: logits + softmax ----------
__global__ void final_kernel(const float* __restrict__ dsum, const float* __restrict__ pooled,
                             const float* __restrict__ ow, const float* __restrict__ ob,
                             float* __restrict__ out) {
    int t = threadIdx.x;
    if (t >= 16) return;
    float d = dsum[t];
    float l0 = ob[0], l1 = ob[1];
    for (int i = 0; i < 32; i++) {
        float p = pooled[t * 32 + i] / d;
        l0 += p * ow[i * 2 + 0];
        l1 += p * ow[i * 2 + 1];
    }
    float m = fmaxf(l0, l1);
    float e0 = __expf(l0 - m), e1 = __expf(l1 - m);
    float s = e0 + e1;
    out[t * 2 + 0] = e0 / s;
    out[t * 2 + 1] = e1 / s;
    out[32 + t * 2 + 0] = l0;
    out[32 + t * 2 + 1] = l1;
}

extern "C" void kernel_launch(void* const* d_in, const int* in_sizes, int n_in,
                              void* d_out, int out_size, void* d_ws, size_t ws_size,
                              hipStream_t stream) {
    const float* x       = (const float*)d_in[0];
    const int*   ei      = (const int*)d_in[1];
    const int*   batch   = (const int*)d_in[2];
    const float* lin0_w  = (const float*)d_in[3];
    const float* lin0_b  = (const float*)d_in[4];
    const float* s1_lw   = (const float*)d_in[5];
    const float* s1_lb   = (const float*)d_in[6];
    const float* s1_rw   = (const float*)d_in[7];
    const float* s2_lw   = (const float*)d_in[8];
    const float* s2_lb   = (const float*)d_in[9];
    const float* s2_rw   = (const float*)d_in[10];
    const float* e0w     = (const float*)d_in[11];
    const float* e0b     = (const float*)d_in[12];
    const float* e1w     = (const float*)d_in[13];
    const float* e1b     = (const float*)d_in[14];
    const float* e2w     = (const float*)d_in[15];
    const float* e2b     = (const float*)d_in[16];
    const float* mw      = (const float*)d_in[17];
    const float* mb      = (const float*)d_in[18];
    const float* gw      = (const float*)d_in[19];
    const float* gb      = (const float*)d_in[20];
    const float* vw      = (const float*)d_in[21];
    const float* vb      = (const float*)d_in[22];
    const float* ow      = (const float*)d_in[23];
    const float* ob      = (const float*)d_in[24];
    float* out = (float*)d_out;

    const int N = N_NODES, E = N_EDGES;
    const int* src = ei;
    const int* dst = ei + E;

    // workspace carve
    char* p = (char*)d_ws;
    auto carve = [&](size_t bytes) { char* r = p; p += (bytes + 255) & ~(size_t)255; return (void*)r; };
    float* x0      = (float*)carve((size_t)N * 64 * 4);
    float* x1      = (float*)carve((size_t)N * 64 * 4);
    float* x2      = (float*)carve((size_t)N * 64 * 4);
    float* meanb   = (float*)carve((size_t)N * 64 * 4);
    float* vbuf    = (float*)carve((size_t)N * 32 * 4);
    float* gbuf    = (float*)carve((size_t)N * 4);
    int*   csr     = (int*)carve((size_t)E * 4);
    int*   deg     = (int*)carve((size_t)N * 4);
    int*   rowstart= (int*)carve((size_t)(N + 1) * 4);
    int*   cursor  = (int*)carve((size_t)N * 4);
    unsigned* mkey = (unsigned*)carve(16 * 4);
    float* dsum    = (float*)carve(16 * 4);
    float* pooled  = (float*)carve(16 * 32 * 4);

    hipMemsetAsync(deg, 0, (size_t)N * 4, stream);
    hipMemsetAsync(mkey, 0, 16 * 4, stream);
    hipMemsetAsync(dsum, 0, 16 * 4, stream);
    hipMemsetAsync(pooled, 0, 16 * 32 * 4, stream);

    int ebl = (E + 255) / 256;
    int nbl = (N + 255) / 256;
    int abl = (N + 3) / 4;

    count_kernel<<<ebl, 256, 0, stream>>>(dst, deg, E);
    scan_kernel<<<1, 1024, 0, stream>>>(deg, rowstart, cursor, N);
    csrfill_kernel<<<ebl, 256, 0, stream>>>(src, dst, cursor, csr, E);

    lin0_kernel<<<nbl, 256, 0, stream>>>(x, lin0_w, lin0_b, x0, N);

    agg_kernel<<<abl, 256, 0, stream>>>(x0, rowstart, csr, meanb, N);
    sage_kernel<<<nbl, 256, 0, stream>>>(meanb, x0, s1_lw, s1_lb, s1_rw, x1, N);

    agg_kernel<<<abl, 256, 0, stream>>>(x1, rowstart, csr, meanb, N);
    sage_kernel<<<nbl, 256, 0, stream>>>(meanb, x1, s2_lw, s2_lb, s2_rw, x2, N);

    head_kernel<<<nbl, 256, 0, stream>>>(x0, x1, x2, batch,
                                         e0w, e0b, e1w, e1b, e2w, e2b,
                                         mw, mb, gw, gb, vw, vb,
                                         gbuf, vbuf, mkey, N);

    pool_kernel<<<nbl, 256, 0, stream>>>(gbuf, vbuf, batch, mkey, dsum, pooled, N);

    final_kernel<<<1, 64, 0, stream>>>(dsum, pooled, ow, ob, out);
}

// Round 2
// 1230.627 us; speedup vs baseline: 2.2739x; 2.2739x over previous
//
#include <hip/hip_runtime.h>
#include <hip/hip_bf16.h>

#define N_NODES 100000
#define N_EDGES 3200000
#define HID 64
#define GDIM 32
#define NUM_GRAPHS 16

// ---------- helpers ----------
__device__ __forceinline__ unsigned fkey(float f) {
    unsigned u = __float_as_uint(f);
    return (u & 0x80000000u) ? ~u : (u | 0x80000000u);
}
__device__ __forceinline__ float funkey(unsigned k) {
    unsigned u = (k & 0x80000000u) ? (k ^ 0x80000000u) : ~k;
    return __uint_as_float(u);
}

// ---------- CSR build ----------
__global__ __launch_bounds__(256) void count_kernel(const int* __restrict__ dst, int* __restrict__ deg, int E) {
    int e = blockIdx.x * blockDim.x + threadIdx.x;
    if (e < E) atomicAdd(&deg[dst[e]], 1);
}

__global__ __launch_bounds__(1024) void scan_kernel(const int* __restrict__ deg, int* __restrict__ rowstart,
                            int* __restrict__ cursor, int N) {
    __shared__ int part[1024];
    int t = threadIdx.x;
    const int CH = (N + 1023) / 1024;
    int lo = t * CH, hi = min(lo + CH, N);
    int s = 0;
    for (int i = lo; i < hi; i++) s += deg[i];
    part[t] = s;
    __syncthreads();
    for (int off = 1; off < 1024; off <<= 1) {
        int v = (t >= off) ? part[t - off] : 0;
        __syncthreads();
        part[t] += v;
        __syncthreads();
    }
    int run = (t == 0) ? 0 : part[t - 1];
    for (int i = lo; i < hi; i++) {
        rowstart[i] = run; cursor[i] = run; run += deg[i];
    }
    if (t == 1023) rowstart[N] = part[1023];
}

__global__ __launch_bounds__(256) void csrfill_kernel(const int* __restrict__ src, const int* __restrict__ dst,
                               int* __restrict__ cursor, int* __restrict__ csr, int E) {
    int e = blockIdx.x * blockDim.x + threadIdx.x;
    if (e < E) {
        int d = dst[e];
        int pos = atomicAdd(&cursor[d], 1);
        csr[pos] = src[e];
    }
}

// ---------- lin0: y = x @ W + b  (N x 64) ----------
__global__ __launch_bounds__(256) void lin0_kernel(const float* __restrict__ x, const float* __restrict__ W,
                            const float* __restrict__ b, float* __restrict__ y, int N) {
    __shared__ __align__(16) float Wl[64 * 64];
    __shared__ float bl[64];
    int t = threadIdx.x;
    for (int i = t; i < 64 * 64; i += 256) Wl[i] = W[i];
    if (t < 64) bl[t] = b[t];
    __syncthreads();
    int row = blockIdx.x * 256 + t;
    if (row >= N) return;
    float acc[64];
#pragma unroll
    for (int j = 0; j < 64; j++) acc[j] = bl[j];
    const float4* xr = (const float4*)(x + (size_t)row * 64);
#pragma unroll
    for (int c = 0; c < 16; c++) {
        float4 xv = xr[c];
        float xs[4] = {xv.x, xv.y, xv.z, xv.w};
#pragma unroll
        for (int kk = 0; kk < 4; kk++) {
            int k = c * 4 + kk;
#pragma unroll
            for (int j4 = 0; j4 < 16; j4++) {
                float4 w = *(const float4*)&Wl[k * 64 + j4 * 4];
                acc[j4 * 4 + 0] += xs[kk] * w.x;
                acc[j4 * 4 + 1] += xs[kk] * w.y;
                acc[j4 * 4 + 2] += xs[kk] * w.z;
                acc[j4 * 4 + 3] += xs[kk] * w.w;
            }
        }
    }
    float4* yr = (float4*)(y + (size_t)row * 64);
#pragma unroll
    for (int c = 0; c < 16; c++)
        yr[c] = make_float4(acc[c * 4], acc[c * 4 + 1], acc[c * 4 + 2], acc[c * 4 + 3]);
}

// ---------- mean aggregation: one wave per node, lane = feature ----------
__global__ __launch_bounds__(256) void agg_kernel(const float* __restrict__ xin, const int* __restrict__ rowstart,
                           const int* __restrict__ csr, float* __restrict__ meanout, int N) {
    int wid = threadIdx.x >> 6, lane = threadIdx.x & 63;
    int node = blockIdx.x * (blockDim.x >> 6) + wid;
    if (node >= N) return;
    int ro = rowstart[node], re = rowstart[node + 1];
    float acc = 0.f;
    for (int base = ro; base < re; base += 64) {
        int rem = re - base;
        int idx = 0;
        if (lane < rem) idx = csr[base + lane];
        int kmax = rem < 64 ? rem : 64;
        for (int k = 0; k < kmax; k++) {
            int s = __shfl(idx, k);
            acc += xin[(size_t)s * 64 + lane];
        }
    }
    int deg = re - ro;
    float inv = 1.0f / (float)(deg > 0 ? deg : 1);
    meanout[(size_t)node * 64 + lane] = acc * inv;
}

// ---------- sage: xout = mean @ LW + lb + xin @ RW ----------
__global__ __launch_bounds__(256) void sage_kernel(const float* __restrict__ mean, const float* __restrict__ xin,
                            const float* __restrict__ lw, const float* __restrict__ lb,
                            const float* __restrict__ rw, float* __restrict__ xout, int N) {
    __shared__ __align__(16) float LW[64 * 64];
    __shared__ __align__(16) float RW[64 * 64];
    __shared__ float LB[64];
    int t = threadIdx.x;
    for (int i = t; i < 64 * 64; i += 256) { LW[i] = lw[i]; RW[i] = rw[i]; }
    if (t < 64) LB[t] = lb[t];
    __syncthreads();
    int row = blockIdx.x * 256 + t;
    if (row >= N) return;
    float acc[64];
#pragma unroll
    for (int j = 0; j < 64; j++) acc[j] = LB[j];
    const float4* mr = (const float4*)(mean + (size_t)row * 64);
    const float4* xr = (const float4*)(xin + (size_t)row * 64);
#pragma unroll
    for (int c = 0; c < 16; c++) {
        float4 xv = mr[c];
        float xs[4] = {xv.x, xv.y, xv.z, xv.w};
#pragma unroll
        for (int kk = 0; kk < 4; kk++) {
            int k = c * 4 + kk;
#pragma unroll
            for (int j4 = 0; j4 < 16; j4++) {
                float4 w = *(const float4*)&LW[k * 64 + j4 * 4];
                acc[j4 * 4 + 0] += xs[kk] * w.x;
                acc[j4 * 4 + 1] += xs[kk] * w.y;
                acc[j4 * 4 + 2] += xs[kk] * w.z;
                acc[j4 * 4 + 3] += xs[kk] * w.w;
            }
        }
    }
#pragma unroll
    for (int c = 0; c < 16; c++) {
        float4 xv = xr[c];
        float xs[4] = {xv.x, xv.y, xv.z, xv.w};
#pragma unroll
        for (int kk = 0; kk < 4; kk++) {
            int k = c * 4 + kk;
#pragma unroll
            for (int j4 = 0; j4 < 16; j4++) {
                float4 w = *(const float4*)&RW[k * 64 + j4 * 4];
                acc[j4 * 4 + 0] += xs[kk] * w.x;
                acc[j4 * 4 + 1] += xs[kk] * w.y;
                acc[j4 * 4 + 2] += xs[kk] * w.z;
                acc[j4 * 4 + 3] += xs[kk] * w.w;
            }
        }
    }
    float4* yr = (float4*)(xout + (size_t)row * 64);
#pragma unroll
    for (int c = 0; c < 16; c++)
        yr[c] = make_float4(acc[c * 4], acc[c * 4 + 1], acc[c * 4 + 2], acc[c * 4 + 3]);
}

// ---------- head: e0..e2, merge, gate, v; per-graph max of g ----------
__global__ __launch_bounds__(256) void head_kernel(const float* __restrict__ x0, const float* __restrict__ x1,
                            const float* __restrict__ x2, const int* __restrict__ batch,
                            const float* __restrict__ e0w, const float* __restrict__ e0b,
                            const float* __restrict__ e1w, const float* __restrict__ e1b,
                            const float* __restrict__ e2w, const float* __restrict__ e2b,
                            const float* __restrict__ mw, const float* __restrict__ mb,
                            const float* __restrict__ gw, const float* __restrict__ gbp,
                            const float* __restrict__ vw, const float* __restrict__ vb,
                            float* __restrict__ gout, float* __restrict__ vout,
                            unsigned* __restrict__ mkey, int N) {
    __shared__ __align__(16) float EW[3 * 64 * 32];
    __shared__ __align__(16) float MW[96 * 32];
    __shared__ __align__(16) float VW[32 * 32];
    __shared__ float EB[96], MB[32], GW[32], VB[32];
    __shared__ float GB;
    __shared__ unsigned smax[16];
    int t = threadIdx.x;
    for (int i = t; i < 2048; i += 256) { EW[i] = e0w[i]; EW[2048 + i] = e1w[i]; EW[4096 + i] = e2w[i]; }
    for (int i = t; i < 3072; i += 256) MW[i] = mw[i];
    for (int i = t; i < 1024; i += 256) VW[i] = vw[i];
    if (t < 32) { EB[t] = e0b[t]; EB[32 + t] = e1b[t]; EB[64 + t] = e2b[t];
                  MB[t] = mb[t]; GW[t] = gw[t]; VB[t] = vb[t]; }
    if (t == 0) GB = gbp[0];
    if (t < 16) smax[t] = 0u;
    __syncthreads();
    int node = blockIdx.x * 256 + t;
    if (node < N) {
        float xc[32];
#pragma unroll
        for (int j = 0; j < 32; j++) xc[j] = MB[j];
        const float* px[3] = {x0 + (size_t)node * 64, x1 + (size_t)node * 64, x2 + (size_t)node * 64};
        for (int h = 0; h < 3; h++) {
            float e[32];
#pragma unroll
            for (int j = 0; j < 32; j++) e[j] = EB[h * 32 + j];
            const float4* xr = (const float4*)px[h];
#pragma unroll
            for (int c = 0; c < 16; c++) {
                float4 xv = xr[c];
                float xs[4] = {xv.x, xv.y, xv.z, xv.w};
#pragma unroll
                for (int kk = 0; kk < 4; kk++) {
                    int k = c * 4 + kk;
#pragma unroll
                    for (int j4 = 0; j4 < 8; j4++) {
                        float4 w = *(const float4*)&EW[h * 2048 + k * 32 + j4 * 4];
                        e[j4 * 4 + 0] += xs[kk] * w.x;
                        e[j4 * 4 + 1] += xs[kk] * w.y;
                        e[j4 * 4 + 2] += xs[kk] * w.z;
                        e[j4 * 4 + 3] += xs[kk] * w.w;
                    }
                }
            }
#pragma unroll
            for (int j = 0; j < 32; j++) e[j] = fmaxf(e[j], 0.f);
#pragma unroll
            for (int i = 0; i < 32; i++) {
#pragma unroll
                for (int j4 = 0; j4 < 8; j4++) {
                    float4 w = *(const float4*)&MW[(h * 32 + i) * 32 + j4 * 4];
                    xc[j4 * 4 + 0] += e[i] * w.x;
                    xc[j4 * 4 + 1] += e[i] * w.y;
                    xc[j4 * 4 + 2] += e[i] * w.z;
                    xc[j4 * 4 + 3] += e[i] * w.w;
                }
            }
        }
#pragma unroll
        for (int j = 0; j < 32; j++) xc[j] = fmaxf(xc[j], 0.f);
        float g = GB;
#pragma unroll
        for (int i = 0; i < 32; i++) g += xc[i] * GW[i];
        float vv[32];
#pragma unroll
        for (int j = 0; j < 32; j++) vv[j] = VB[j];
#pragma unroll
        for (int i = 0; i < 32; i++) {
#pragma unroll
            for (int j4 = 0; j4 < 8; j4++) {
                float4 w = *(const float4*)&VW[i * 32 + j4 * 4];
                vv[j4 * 4 + 0] += xc[i] * w.x;
                vv[j4 * 4 + 1] += xc[i] * w.y;
                vv[j4 * 4 + 2] += xc[i] * w.z;
                vv[j4 * 4 + 3] += xc[i] * w.w;
            }
        }
        gout[node] = g;
        float4* vr = (float4*)(vout + (size_t)node * 32);
#pragma unroll
        for (int c = 0; c < 8; c++)
            vr[c] = make_float4(vv[c * 4], vv[c * 4 + 1], vv[c * 4 + 2], vv[c * 4 + 3]);
        int b = batch[node];
        atomicMax(&smax[b], fkey(g));
    }
    __syncthreads();
    if (t < 16) atomicMax(&mkey[t], smax[t]);
}

// ---------- pool: d = seg_sum(e), num = seg_sum(e*v) ----------
__global__ __launch_bounds__(256) void pool_kernel(const float* __restrict__ g, const float* __restrict__ v,
                            const int* __restrict__ batch, const unsigned* __restrict__ mkey,
                            float* __restrict__ dsum, float* __restrict__ pooled, int N) {
    __shared__ float sd[16];
    __shared__ float sp[16 * 32];
    __shared__ float sm[16];
    int t = threadIdx.x;
    if (t < 16) { sd[t] = 0.f; sm[t] = funkey(mkey[t]); }
    for (int i = t; i < 512; i += 256) sp[i] = 0.f;
    __syncthreads();
    int node = blockIdx.x * 256 + t;
    if (node < N) {
        int b = batch[node];
        float e = __expf(g[node] - sm[b]);
        atomicAdd(&sd[b], e);
        const float4* vr = (const float4*)(v + (size_t)node * 32);
#pragma unroll
        for (int c = 0; c < 8; c++) {
            float4 vv = vr[c];
            atomicAdd(&sp[b * 32 + c * 4 + 0], e * vv.x);
            atomicAdd(&sp[b * 32 + c * 4 + 1], e * vv.y);
            atomicAdd(&sp[b * 32 + c * 4 + 2], e * vv.z);
            atomicAdd(&sp[b * 32 + c * 4 + 3], e * vv.w);
        }
    }
    __syncthreads();
    if (t < 16) atomicAdd(&dsum[t], sd[t]);
    for (int i = t; i < 512; i += 256) atomicAdd(&pooled[i], sp[i]);
}

// ---------- final: logits + softmax ----------
__global__ __launch_bounds__(64) void final_kernel(const float* __restrict__ dsum, const float* __restrict__ pooled,
                             const float* __restrict__ ow, const float* __restrict__ ob,
                             float* __restrict__ out) {
    int t = threadIdx.x;
    if (t >= 16) return;
    float d = dsum[t];
    float l0 = ob[0], l1 = ob[1];
    for (int i = 0; i < 32; i++) {
        float p = pooled[t * 32 + i] / d;
        l0 += p * ow[i * 2 + 0];
        l1 += p * ow[i * 2 + 1];
    }
    float m = fmaxf(l0, l1);
    float e0 = __expf(l0 - m), e1 = __expf(l1 - m);
    float s = e0 + e1;
    out[t * 2 + 0] = e0 / s;
    out[t * 2 + 1] = e1 / s;
    out[32 + t * 2 + 0] = l0;
    out[32 + t * 2 + 1] = l1;
}

extern "C" void kernel_launch(void* const* d_in, const int* in_sizes, int n_in,
                              void* d_out, int out_size, void* d_ws, size_t ws_size,
                              hipStream_t stream) {
    const float* x       = (const float*)d_in[0];
    const int*   ei      = (const int*)d_in[1];
    const int*   batch   = (const int*)d_in[2];
    const float* lin0_w  = (const float*)d_in[3];
    const float* lin0_b  = (const float*)d_in[4];
    const float* s1_lw   = (const float*)d_in[5];
    const float* s1_lb   = (const float*)d_in[6];
    const float* s1_rw   = (const float*)d_in[7];
    const float* s2_lw   = (const float*)d_in[8];
    const float* s2_lb   = (const float*)d_in[9];
    const float* s2_rw   = (const float*)d_in[10];
    const float* e0w     = (const float*)d_in[11];
    const float* e0b     = (const float*)d_in[12];
    const float* e1w     = (const float*)d_in[13];
    const float* e1b     = (const float*)d_in[14];
    const float* e2w     = (const float*)d_in[15];
    const float* e2b     = (const float*)d_in[16];
    const float* mw      = (const float*)d_in[17];
    const float* mb      = (const float*)d_in[18];
    const float* gw      = (const float*)d_in[19];
    const float* gb      = (const float*)d_in[20];
    const float* vw      = (const float*)d_in[21];
    const float* vb      = (const float*)d_in[22];
    const float* ow      = (const float*)d_in[23];
    const float* ob      = (const float*)d_in[24];
    float* out = (float*)d_out;

    const int N = N_NODES, E = N_EDGES;
    const int* src = ei;
    const int* dst = ei + E;

    // workspace carve
    char* p = (char*)d_ws;
    auto carve = [&](size_t bytes) { char* r = p; p += (bytes + 255) & ~(size_t)255; return (void*)r; };
    float* x0      = (float*)carve((size_t)N * 64 * 4);
    float* x1      = (float*)carve((size_t)N * 64 * 4);
    float* x2      = (float*)carve((size_t)N * 64 * 4);
    float* meanb   = (float*)carve((size_t)N * 64 * 4);
    float* vbuf    = (float*)carve((size_t)N * 32 * 4);
    float* gbuf    = (float*)carve((size_t)N * 4);
    int*   csr     = (int*)carve((size_t)E * 4);
    int*   deg     = (int*)carve((size_t)N * 4);
    int*   rowstart= (int*)carve((size_t)(N + 1) * 4);
    int*   cursor  = (int*)carve((size_t)N * 4);
    unsigned* mkey = (unsigned*)carve(16 * 4);
    float* dsum    = (float*)carve(16 * 4);
    float* pooled  = (float*)carve(16 * 32 * 4);

    hipMemsetAsync(deg, 0, (size_t)N * 4, stream);
    hipMemsetAsync(mkey, 0, 16 * 4, stream);
    hipMemsetAsync(dsum, 0, 16 * 4, stream);
    hipMemsetAsync(pooled, 0, 16 * 32 * 4, stream);

    int ebl = (E + 255) / 256;
    int nbl = (N + 255) / 256;
    int abl = (N + 3) / 4;

    count_kernel<<<ebl, 256, 0, stream>>>(dst, deg, E);
    scan_kernel<<<1, 1024, 0, stream>>>(deg, rowstart, cursor, N);
    csrfill_kernel<<<ebl, 256, 0, stream>>>(src, dst, cursor, csr, E);

    lin0_kernel<<<nbl, 256, 0, stream>>>(x, lin0_w, lin0_b, x0, N);

    agg_kernel<<<abl, 256, 0, stream>>>(x0, rowstart, csr, meanb, N);
    sage_kernel<<<nbl, 256, 0, stream>>>(meanb, x0, s1_lw, s1_lb, s1_rw, x1, N);

    agg_kernel<<<abl, 256, 0, stream>>>(x1, rowstart, csr, meanb, N);
    sage_kernel<<<nbl, 256, 0, stream>>>(meanb, x1, s2_lw, s2_lb, s2_rw, x2, N);

    head_kernel<<<nbl, 256, 0, stream>>>(x0, x1, x2, batch,
                                         e0w, e0b, e1w, e1b, e2w, e2b,
                                         mw, mb, gw, gb, vw, vb,
                                         gbuf, vbuf, mkey, N);

    pool_kernel<<<nbl, 256, 0, stream>>>(gbuf, vbuf, batch, mkey, dsum, pooled, N);

    final_kernel<<<1, 64, 0, stream>>>(dsum, pooled, ow, ob, out);
}

// Round 3
// 800.414 us; speedup vs baseline: 3.4960x; 1.5375x over previous
//
#include <hip/hip_runtime.h>
#include <hip/hip_bf16.h>

#define N_NODES 100000
#define N_EDGES 3200000
#define HID 64
#define GDIM 32
#define NUM_GRAPHS 16

// ---------- helpers ----------
__device__ __forceinline__ unsigned fkey(float f) {
    unsigned u = __float_as_uint(f);
    return (u & 0x80000000u) ? ~u : (u | 0x80000000u);
}
__device__ __forceinline__ float funkey(unsigned k) {
    unsigned u = (k & 0x80000000u) ? (k ^ 0x80000000u) : ~k;
    return __uint_as_float(u);
}

// ---------- CSR build ----------
// phase 1: deg histogram + per-edge position within its dst bucket (coalesced write)
__global__ __launch_bounds__(256) void count_kernel(const int* __restrict__ dst, int* __restrict__ deg,
                                                    int* __restrict__ pos, int E4) {
    int t = blockIdx.x * blockDim.x + threadIdx.x;
    if (t >= E4) return;
    int4 d = ((const int4*)dst)[t];
    int4 p;
    p.x = atomicAdd(&deg[d.x], 1);
    p.y = atomicAdd(&deg[d.y], 1);
    p.z = atomicAdd(&deg[d.z], 1);
    p.w = atomicAdd(&deg[d.w], 1);
    ((int4*)pos)[t] = p;
}

__global__ __launch_bounds__(1024) void scan_kernel(const int* __restrict__ deg, int* __restrict__ rowstart, int N) {
    __shared__ int part[1024];
    int t = threadIdx.x;
    const int CH = (N + 1023) / 1024;
    int lo = t * CH, hi = min(lo + CH, N);
    int s = 0;
    for (int i = lo; i < hi; i++) s += deg[i];
    part[t] = s;
    __syncthreads();
    for (int off = 1; off < 1024; off <<= 1) {
        int v = (t >= off) ? part[t - off] : 0;
        __syncthreads();
        part[t] += v;
        __syncthreads();
    }
    int run = (t == 0) ? 0 : part[t - 1];
    for (int i = lo; i < hi; i++) {
        rowstart[i] = run; run += deg[i];
    }
    if (t == 1023) rowstart[N] = part[1023];
}

// phase 3: atomic-free scatter fill
__global__ __launch_bounds__(256) void fill_kernel(const int* __restrict__ src, const int* __restrict__ dst,
                                                   const int* __restrict__ pos, const int* __restrict__ rowstart,
                                                   int* __restrict__ csr, int E4) {
    int t = blockIdx.x * blockDim.x + threadIdx.x;
    if (t >= E4) return;
    int4 d = ((const int4*)dst)[t];
    int4 p = ((const int4*)pos)[t];
    int4 s = ((const int4*)src)[t];
    int r0 = rowstart[d.x];
    int r1 = rowstart[d.y];
    int r2 = rowstart[d.z];
    int r3 = rowstart[d.w];
    csr[r0 + p.x] = s.x;
    csr[r1 + p.y] = s.y;
    csr[r2 + p.z] = s.z;
    csr[r3 + p.w] = s.w;
}

// ---------- lin0: y = x @ W + b  (N x 64) ----------
__global__ __launch_bounds__(256) void lin0_kernel(const float* __restrict__ x, const float* __restrict__ W,
                            const float* __restrict__ b, float* __restrict__ y, int N) {
    __shared__ __align__(16) float Wl[64 * 64];
    __shared__ float bl[64];
    int t = threadIdx.x;
    for (int i = t; i < 64 * 64; i += 256) Wl[i] = W[i];
    if (t < 64) bl[t] = b[t];
    __syncthreads();
    int row = blockIdx.x * 256 + t;
    if (row >= N) return;
    float acc[64];
#pragma unroll
    for (int j = 0; j < 64; j++) acc[j] = bl[j];
    const float4* xr = (const float4*)(x + (size_t)row * 64);
#pragma unroll
    for (int c = 0; c < 16; c++) {
        float4 xv = xr[c];
        float xs[4] = {xv.x, xv.y, xv.z, xv.w};
#pragma unroll
        for (int kk = 0; kk < 4; kk++) {
            int k = c * 4 + kk;
#pragma unroll
            for (int j4 = 0; j4 < 16; j4++) {
                float4 w = *(const float4*)&Wl[k * 64 + j4 * 4];
                acc[j4 * 4 + 0] += xs[kk] * w.x;
                acc[j4 * 4 + 1] += xs[kk] * w.y;
                acc[j4 * 4 + 2] += xs[kk] * w.z;
                acc[j4 * 4 + 3] += xs[kk] * w.w;
            }
        }
    }
    float4* yr = (float4*)(y + (size_t)row * 64);
#pragma unroll
    for (int c = 0; c < 16; c++)
        yr[c] = make_float4(acc[c * 4], acc[c * 4 + 1], acc[c * 4 + 2], acc[c * 4 + 3]);
}

// ---------- mean aggregation: one wave per node, 4 edges x 16 lanes x float4 ----------
__global__ __launch_bounds__(256) void agg_kernel(const float* __restrict__ xin, const int* __restrict__ rowstart,
                           const int* __restrict__ csr, float* __restrict__ meanout, int N) {
    int wid = threadIdx.x >> 6, lane = threadIdx.x & 63;
    int node = blockIdx.x * 4 + wid;
    if (node >= N) return;
    int ro = rowstart[node], re = rowstart[node + 1];
    int g = lane >> 4, c4 = lane & 15;
    float4 acc = make_float4(0.f, 0.f, 0.f, 0.f);
    for (int base = ro; base < re; base += 64) {
        int rem = re - base;
        int idx = 0;
        if (lane < rem) idx = csr[base + lane];
        int kmax = rem < 64 ? rem : 64;
        for (int k = 0; k < kmax; k += 4) {
            int e = k + g;
            int s = __shfl(idx, e);
            if (e < kmax) {
                float4 xv = *(const float4*)(xin + (size_t)s * 64 + c4 * 4);
                acc.x += xv.x; acc.y += xv.y; acc.z += xv.z; acc.w += xv.w;
            }
        }
    }
#pragma unroll
    for (int off = 16; off < 64; off <<= 1) {
        acc.x += __shfl_xor(acc.x, off);
        acc.y += __shfl_xor(acc.y, off);
        acc.z += __shfl_xor(acc.z, off);
        acc.w += __shfl_xor(acc.w, off);
    }
    int deg = re - ro;
    float inv = 1.0f / (float)(deg > 0 ? deg : 1);
    if (lane < 16) {
        ((float4*)(meanout + (size_t)node * 64))[c4] =
            make_float4(acc.x * inv, acc.y * inv, acc.z * inv, acc.w * inv);
    }
}

// ---------- sage: xout = mean @ LW + lb + xin @ RW ----------
__global__ __launch_bounds__(256) void sage_kernel(const float* __restrict__ mean, const float* __restrict__ xin,
                            const float* __restrict__ lw, const float* __restrict__ lb,
                            const float* __restrict__ rw, float* __restrict__ xout, int N) {
    __shared__ __align__(16) float LW[64 * 64];
    __shared__ __align__(16) float RW[64 * 64];
    __shared__ float LB[64];
    int t = threadIdx.x;
    for (int i = t; i < 64 * 64; i += 256) { LW[i] = lw[i]; RW[i] = rw[i]; }
    if (t < 64) LB[t] = lb[t];
    __syncthreads();
    int row = blockIdx.x * 256 + t;
    if (row >= N) return;
    float acc[64];
#pragma unroll
    for (int j = 0; j < 64; j++) acc[j] = LB[j];
    const float4* mr = (const float4*)(mean + (size_t)row * 64);
    const float4* xr = (const float4*)(xin + (size_t)row * 64);
#pragma unroll
    for (int c = 0; c < 16; c++) {
        float4 xv = mr[c];
        float xs[4] = {xv.x, xv.y, xv.z, xv.w};
#pragma unroll
        for (int kk = 0; kk < 4; kk++) {
            int k = c * 4 + kk;
#pragma unroll
            for (int j4 = 0; j4 < 16; j4++) {
                float4 w = *(const float4*)&LW[k * 64 + j4 * 4];
                acc[j4 * 4 + 0] += xs[kk] * w.x;
                acc[j4 * 4 + 1] += xs[kk] * w.y;
                acc[j4 * 4 + 2] += xs[kk] * w.z;
                acc[j4 * 4 + 3] += xs[kk] * w.w;
            }
        }
    }
#pragma unroll
    for (int c = 0; c < 16; c++) {
        float4 xv = xr[c];
        float xs[4] = {xv.x, xv.y, xv.z, xv.w};
#pragma unroll
        for (int kk = 0; kk < 4; kk++) {
            int k = c * 4 + kk;
#pragma unroll
            for (int j4 = 0; j4 < 16; j4++) {
                float4 w = *(const float4*)&RW[k * 64 + j4 * 4];
                acc[j4 * 4 + 0] += xs[kk] * w.x;
                acc[j4 * 4 + 1] += xs[kk] * w.y;
                acc[j4 * 4 + 2] += xs[kk] * w.z;
                acc[j4 * 4 + 3] += xs[kk] * w.w;
            }
        }
    }
    float4* yr = (float4*)(xout + (size_t)row * 64);
#pragma unroll
    for (int c = 0; c < 16; c++)
        yr[c] = make_float4(acc[c * 4], acc[c * 4 + 1], acc[c * 4 + 2], acc[c * 4 + 3]);
}

// ---------- head: e0..e2, merge, gate, v; per-graph max of g ----------
__global__ __launch_bounds__(256) void head_kernel(const float* __restrict__ x0, const float* __restrict__ x1,
                            const float* __restrict__ x2, const int* __restrict__ batch,
                            const float* __restrict__ e0w, const float* __restrict__ e0b,
                            const float* __restrict__ e1w, const float* __restrict__ e1b,
                            const float* __restrict__ e2w, const float* __restrict__ e2b,
                            const float* __restrict__ mw, const float* __restrict__ mb,
                            const float* __restrict__ gw, const float* __restrict__ gbp,
                            const float* __restrict__ vw, const float* __restrict__ vb,
                            float* __restrict__ gout, float* __restrict__ vout,
                            unsigned* __restrict__ mkey, int N) {
    __shared__ __align__(16) float EW[3 * 64 * 32];
    __shared__ __align__(16) float MW[96 * 32];
    __shared__ __align__(16) float VW[32 * 32];
    __shared__ float EB[96], MB[32], GW[32], VB[32];
    __shared__ float GB;
    __shared__ unsigned smax[16];
    int t = threadIdx.x;
    for (int i = t; i < 2048; i += 256) { EW[i] = e0w[i]; EW[2048 + i] = e1w[i]; EW[4096 + i] = e2w[i]; }
    for (int i = t; i < 3072; i += 256) MW[i] = mw[i];
    for (int i = t; i < 1024; i += 256) VW[i] = vw[i];
    if (t < 32) { EB[t] = e0b[t]; EB[32 + t] = e1b[t]; EB[64 + t] = e2b[t];
                  MB[t] = mb[t]; GW[t] = gw[t]; VB[t] = vb[t]; }
    if (t == 0) GB = gbp[0];
    if (t < 16) smax[t] = 0u;
    __syncthreads();
    int node = blockIdx.x * 256 + t;
    if (node < N) {
        float xc[32];
#pragma unroll
        for (int j = 0; j < 32; j++) xc[j] = MB[j];
        const float* px[3] = {x0 + (size_t)node * 64, x1 + (size_t)node * 64, x2 + (size_t)node * 64};
        for (int h = 0; h < 3; h++) {
            float e[32];
#pragma unroll
            for (int j = 0; j < 32; j++) e[j] = EB[h * 32 + j];
            const float4* xr = (const float4*)px[h];
#pragma unroll
            for (int c = 0; c < 16; c++) {
                float4 xv = xr[c];
                float xs[4] = {xv.x, xv.y, xv.z, xv.w};
#pragma unroll
                for (int kk = 0; kk < 4; kk++) {
                    int k = c * 4 + kk;
#pragma unroll
                    for (int j4 = 0; j4 < 8; j4++) {
                        float4 w = *(const float4*)&EW[h * 2048 + k * 32 + j4 * 4];
                        e[j4 * 4 + 0] += xs[kk] * w.x;
                        e[j4 * 4 + 1] += xs[kk] * w.y;
                        e[j4 * 4 + 2] += xs[kk] * w.z;
                        e[j4 * 4 + 3] += xs[kk] * w.w;
                    }
                }
            }
#pragma unroll
            for (int j = 0; j < 32; j++) e[j] = fmaxf(e[j], 0.f);
#pragma unroll
            for (int i = 0; i < 32; i++) {
#pragma unroll
                for (int j4 = 0; j4 < 8; j4++) {
                    float4 w = *(const float4*)&MW[(h * 32 + i) * 32 + j4 * 4];
                    xc[j4 * 4 + 0] += e[i] * w.x;
                    xc[j4 * 4 + 1] += e[i] * w.y;
                    xc[j4 * 4 + 2] += e[i] * w.z;
                    xc[j4 * 4 + 3] += e[i] * w.w;
                }
            }
        }
#pragma unroll
        for (int j = 0; j < 32; j++) xc[j] = fmaxf(xc[j], 0.f);
        float g = GB;
#pragma unroll
        for (int i = 0; i < 32; i++) g += xc[i] * GW[i];
        float vv[32];
#pragma unroll
        for (int j = 0; j < 32; j++) vv[j] = VB[j];
#pragma unroll
        for (int i = 0; i < 32; i++) {
#pragma unroll
            for (int j4 = 0; j4 < 8; j4++) {
                float4 w = *(const float4*)&VW[i * 32 + j4 * 4];
                vv[j4 * 4 + 0] += xc[i] * w.x;
                vv[j4 * 4 + 1] += xc[i] * w.y;
                vv[j4 * 4 + 2] += xc[i] * w.z;
                vv[j4 * 4 + 3] += xc[i] * w.w;
            }
        }
        gout[node] = g;
        float4* vr = (float4*)(vout + (size_t)node * 32);
#pragma unroll
        for (int c = 0; c < 8; c++)
            vr[c] = make_float4(vv[c * 4], vv[c * 4 + 1], vv[c * 4 + 2], vv[c * 4 + 3]);
        int b = batch[node];
        atomicMax(&smax[b], fkey(g));
    }
    __syncthreads();
    if (t < 16) atomicMax(&mkey[t], smax[t]);
}

// ---------- pool: d = seg_sum(e), num = seg_sum(e*v) ----------
__global__ __launch_bounds__(256) void pool_kernel(const float* __restrict__ g, const float* __restrict__ v,
                            const int* __restrict__ batch, const unsigned* __restrict__ mkey,
                            float* __restrict__ dsum, float* __restrict__ pooled, int N) {
    __shared__ float sd[16];
    __shared__ float sp[16 * 32];
    __shared__ float sm[16];
    int t = threadIdx.x;
    if (t < 16) { sd[t] = 0.f; sm[t] = funkey(mkey[t]); }
    for (int i = t; i < 512; i += 256) sp[i] = 0.f;
    __syncthreads();
    int node = blockIdx.x * 256 + t;
    if (node < N) {
        int b = batch[node];
        float e = __expf(g[node] - sm[b]);
        atomicAdd(&sd[b], e);
        const float4* vr = (const float4*)(v + (size_t)node * 32);
#pragma unroll
        for (int c = 0; c < 8; c++) {
            float4 vv = vr[c];
            atomicAdd(&sp[b * 32 + c * 4 + 0], e * vv.x);
            atomicAdd(&sp[b * 32 + c * 4 + 1], e * vv.y);
            atomicAdd(&sp[b * 32 + c * 4 + 2], e * vv.z);
            atomicAdd(&sp[b * 32 + c * 4 + 3], e * vv.w);
        }
    }
    __syncthreads();
    if (t < 16) atomicAdd(&dsum[t], sd[t]);
    for (int i = t; i < 512; i += 256) atomicAdd(&pooled[i], sp[i]);
}

// ---------- final: logits + softmax ----------
__global__ __launch_bounds__(64) void final_kernel(const float* __restrict__ dsum, const float* __restrict__ pooled,
                             const float* __restrict__ ow, const float* __restrict__ ob,
                             float* __restrict__ out) {
    int t = threadIdx.x;
    if (t >= 16) return;
    float d = dsum[t];
    float l0 = ob[0], l1 = ob[1];
    for (int i = 0; i < 32; i++) {
        float p = pooled[t * 32 + i] / d;
        l0 += p * ow[i * 2 + 0];
        l1 += p * ow[i * 2 + 1];
    }
    float m = fmaxf(l0, l1);
    float e0 = __expf(l0 - m), e1 = __expf(l1 - m);
    float s = e0 + e1;
    out[t * 2 + 0] = e0 / s;
    out[t * 2 + 1] = e1 / s;
    out[32 + t * 2 + 0] = l0;
    out[32 + t * 2 + 1] = l1;
}

extern "C" void kernel_launch(void* const* d_in, const int* in_sizes, int n_in,
                              void* d_out, int out_size, void* d_ws, size_t ws_size,
                              hipStream_t stream) {
    const float* x       = (const float*)d_in[0];
    const int*   ei      = (const int*)d_in[1];
    const int*   batch   = (const int*)d_in[2];
    const float* lin0_w  = (const float*)d_in[3];
    const float* lin0_b  = (const float*)d_in[4];
    const float* s1_lw   = (const float*)d_in[5];
    const float* s1_lb   = (const float*)d_in[6];
    const float* s1_rw   = (const float*)d_in[7];
    const float* s2_lw   = (const float*)d_in[8];
    const float* s2_lb   = (const float*)d_in[9];
    const float* s2_rw   = (const float*)d_in[10];
    const float* e0w     = (const float*)d_in[11];
    const float* e0b     = (const float*)d_in[12];
    const float* e1w     = (const float*)d_in[13];
    const float* e1b     = (const float*)d_in[14];
    const float* e2w     = (const float*)d_in[15];
    const float* e2b     = (const float*)d_in[16];
    const float* mw      = (const float*)d_in[17];
    const float* mb      = (const float*)d_in[18];
    const float* gw      = (const float*)d_in[19];
    const float* gb      = (const float*)d_in[20];
    const float* vw      = (const float*)d_in[21];
    const float* vb      = (const float*)d_in[22];
    const float* ow      = (const float*)d_in[23];
    const float* ob      = (const float*)d_in[24];
    float* out = (float*)d_out;

    const int N = N_NODES, E = N_EDGES;
    const int* src = ei;
    const int* dst = ei + E;

    // workspace carve
    char* p = (char*)d_ws;
    auto carve = [&](size_t bytes) { char* r = p; p += (bytes + 255) & ~(size_t)255; return (void*)r; };
    float* x0      = (float*)carve((size_t)N * 64 * 4);
    float* x1      = (float*)carve((size_t)N * 64 * 4);
    float* x2      = (float*)carve((size_t)N * 64 * 4);
    float* meanb   = (float*)carve((size_t)N * 64 * 4);
    float* vbuf    = (float*)carve((size_t)N * 32 * 4);
    float* gbuf    = (float*)carve((size_t)N * 4);
    int*   csr     = (int*)carve((size_t)E * 4);
    int*   pos     = (int*)carve((size_t)E * 4);
    int*   deg     = (int*)carve((size_t)N * 4);
    int*   rowstart= (int*)carve((size_t)(N + 1) * 4);
    unsigned* mkey = (unsigned*)carve(16 * 4);
    float* dsum    = (float*)carve(16 * 4);
    float* pooled  = (float*)carve(16 * 32 * 4);

    hipMemsetAsync(deg, 0, (size_t)N * 4, stream);
    hipMemsetAsync(mkey, 0, 16 * 4, stream);
    hipMemsetAsync(dsum, 0, 16 * 4, stream);
    hipMemsetAsync(pooled, 0, 16 * 32 * 4, stream);

    const int E4 = E / 4;                 // E divisible by 4
    int e4bl = (E4 + 255) / 256;
    int nbl = (N + 255) / 256;
    int abl = (N + 3) / 4;

    count_kernel<<<e4bl, 256, 0, stream>>>(dst, deg, pos, E4);
    scan_kernel<<<1, 1024, 0, stream>>>(deg, rowstart, N);
    fill_kernel<<<e4bl, 256, 0, stream>>>(src, dst, pos, rowstart, csr, E4);

    lin0_kernel<<<nbl, 256, 0, stream>>>(x, lin0_w, lin0_b, x0, N);

    agg_kernel<<<abl, 256, 0, stream>>>(x0, rowstart, csr, meanb, N);
    sage_kernel<<<nbl, 256, 0, stream>>>(meanb, x0, s1_lw, s1_lb, s1_rw, x1, N);

    agg_kernel<<<abl, 256, 0, stream>>>(x1, rowstart, csr, meanb, N);
    sage_kernel<<<nbl, 256, 0, stream>>>(meanb, x1, s2_lw, s2_lb, s2_rw, x2, N);

    head_kernel<<<nbl, 256, 0, stream>>>(x0, x1, x2, batch,
                                         e0w, e0b, e1w, e1b, e2w, e2b,
                                         mw, mb, gw, gb, vw, vb,
                                         gbuf, vbuf, mkey, N);

    pool_kernel<<<nbl, 256, 0, stream>>>(gbuf, vbuf, batch, mkey, dsum, pooled, N);

    final_kernel<<<1, 64, 0, stream>>>(dsum, pooled, ow, ob, out);
}

// Round 4
// 650.428 us; speedup vs baseline: 4.3022x; 1.2306x over previous
//
#include <hip/hip_runtime.h>
#include <hip/hip_bf16.h>

#define N_NODES 100000
#define N_EDGES 3200000
#define HID 64
#define GDIM 32
#define NUM_GRAPHS 16
#define SCAN_CHUNK 2048

// ---------- helpers ----------
__device__ __forceinline__ unsigned fkey(float f) {
    unsigned u = __float_as_uint(f);
    return (u & 0x80000000u) ? ~u : (u | 0x80000000u);
}
__device__ __forceinline__ float funkey(unsigned k) {
    unsigned u = (k & 0x80000000u) ? (k ^ 0x80000000u) : ~k;
    return __uint_as_float(u);
}

// ---------- CSR build ----------
// phase 1: deg histogram + per-edge position within its dst bucket (coalesced write)
__global__ __launch_bounds__(256) void count_kernel(const int* __restrict__ dst, int* __restrict__ deg,
                                                    int* __restrict__ pos, int E4) {
    int t = blockIdx.x * blockDim.x + threadIdx.x;
    if (t >= E4) return;
    int4 d = ((const int4*)dst)[t];
    int4 p;
    p.x = atomicAdd(&deg[d.x], 1);
    p.y = atomicAdd(&deg[d.y], 1);
    p.z = atomicAdd(&deg[d.z], 1);
    p.w = atomicAdd(&deg[d.w], 1);
    ((int4*)pos)[t] = p;
}

// ---------- 3-phase parallel exclusive scan of deg -> rowstart ----------
__global__ __launch_bounds__(256) void scan_partial(const int* __restrict__ deg, int* __restrict__ blocksum, int N) {
    __shared__ int red[4];
    int b = blockIdx.x, t = threadIdx.x;
    int base = b * SCAN_CHUNK + t * 8;
    int s = 0;
#pragma unroll
    for (int j = 0; j < 8; j++) { int i = base + j; s += (i < N) ? deg[i] : 0; }
#pragma unroll
    for (int off = 32; off; off >>= 1) s += __shfl_down(s, off);
    if ((t & 63) == 0) red[t >> 6] = s;
    __syncthreads();
    if (t == 0) blocksum[b] = red[0] + red[1] + red[2] + red[3];
}

__global__ __launch_bounds__(64) void scan_blocksums(const int* __restrict__ blocksum, int* __restrict__ blockoff,
                                                     int* __restrict__ rowstart, int nb, int N) {
    int t = threadIdx.x;
    int own = (t < nb) ? blocksum[t] : 0;
    int v = own;
#pragma unroll
    for (int off = 1; off < 64; off <<= 1) {
        int u = __shfl_up(v, off);
        if (t >= off) v += u;
    }
    if (t < nb) blockoff[t] = v - own;       // exclusive
    if (t == 63) rowstart[N] = v;            // total
}

__global__ __launch_bounds__(256) void scan_scatter(const int* __restrict__ deg, const int* __restrict__ blockoff,
                                                    int* __restrict__ rowstart, int N) {
    __shared__ int ts[256];
    int b = blockIdx.x, t = threadIdx.x;
    int base = b * SCAN_CHUNK + t * 8;
    int d[8]; int s = 0;
#pragma unroll
    for (int j = 0; j < 8; j++) { int i = base + j; d[j] = (i < N) ? deg[i] : 0; s += d[j]; }
    ts[t] = s;
    __syncthreads();
    for (int off = 1; off < 256; off <<= 1) {
        int v = (t >= off) ? ts[t - off] : 0;
        __syncthreads();
        ts[t] += v;
        __syncthreads();
    }
    int excl = (t == 0 ? 0 : ts[t - 1]) + blockoff[b];
#pragma unroll
    for (int j = 0; j < 8; j++) { int i = base + j; if (i < N) rowstart[i] = excl; excl += d[j]; }
}

// phase 3: atomic-free scatter fill
__global__ __launch_bounds__(256) void fill_kernel(const int* __restrict__ src, const int* __restrict__ dst,
                                                   const int* __restrict__ pos, const int* __restrict__ rowstart,
                                                   int* __restrict__ csr, int E4) {
    int t = blockIdx.x * blockDim.x + threadIdx.x;
    if (t >= E4) return;
    int4 d = ((const int4*)dst)[t];
    int4 p = ((const int4*)pos)[t];
    int4 s = ((const int4*)src)[t];
    int r0 = rowstart[d.x];
    int r1 = rowstart[d.y];
    int r2 = rowstart[d.z];
    int r3 = rowstart[d.w];
    csr[r0 + p.x] = s.x;
    csr[r1 + p.y] = s.y;
    csr[r2 + p.z] = s.z;
    csr[r3 + p.w] = s.w;
}

// ---------- lin0: y = x @ W + b  (N x 64) ----------
__global__ __launch_bounds__(256) void lin0_kernel(const float* __restrict__ x, const float* __restrict__ W,
                            const float* __restrict__ b, float* __restrict__ y, int N) {
    __shared__ __align__(16) float Wl[64 * 64];
    __shared__ float bl[64];
    int t = threadIdx.x;
    for (int i = t; i < 64 * 64; i += 256) Wl[i] = W[i];
    if (t < 64) bl[t] = b[t];
    __syncthreads();
    int row = blockIdx.x * 256 + t;
    if (row >= N) return;
    float acc[64];
#pragma unroll
    for (int j = 0; j < 64; j++) acc[j] = bl[j];
    const float4* xr = (const float4*)(x + (size_t)row * 64);
#pragma unroll
    for (int c = 0; c < 16; c++) {
        float4 xv = xr[c];
        float xs[4] = {xv.x, xv.y, xv.z, xv.w};
#pragma unroll
        for (int kk = 0; kk < 4; kk++) {
            int k = c * 4 + kk;
#pragma unroll
            for (int j4 = 0; j4 < 16; j4++) {
                float4 w = *(const float4*)&Wl[k * 64 + j4 * 4];
                acc[j4 * 4 + 0] += xs[kk] * w.x;
                acc[j4 * 4 + 1] += xs[kk] * w.y;
                acc[j4 * 4 + 2] += xs[kk] * w.z;
                acc[j4 * 4 + 3] += xs[kk] * w.w;
            }
        }
    }
    float4* yr = (float4*)(y + (size_t)row * 64);
#pragma unroll
    for (int c = 0; c < 16; c++)
        yr[c] = make_float4(acc[c * 4], acc[c * 4 + 1], acc[c * 4 + 2], acc[c * 4 + 3]);
}

// ---------- mean aggregation: one wave per node, 4 edges x 16 lanes x float4 ----------
__global__ __launch_bounds__(256) void agg_kernel(const float* __restrict__ xin, const int* __restrict__ rowstart,
                           const int* __restrict__ csr, float* __restrict__ meanout, int N) {
    int wid = threadIdx.x >> 6, lane = threadIdx.x & 63;
    int node = blockIdx.x * 4 + wid;
    if (node >= N) return;
    int ro = rowstart[node], re = rowstart[node + 1];
    int g = lane >> 4, c4 = lane & 15;
    float4 acc = make_float4(0.f, 0.f, 0.f, 0.f);
    for (int base = ro; base < re; base += 64) {
        int rem = re - base;
        int idx = 0;
        if (lane < rem) idx = csr[base + lane];
        int kmax = rem < 64 ? rem : 64;
        for (int k = 0; k < kmax; k += 4) {
            int e = k + g;
            int s = __shfl(idx, e);
            if (e < kmax) {
                float4 xv = *(const float4*)(xin + (size_t)s * 64 + c4 * 4);
                acc.x += xv.x; acc.y += xv.y; acc.z += xv.z; acc.w += xv.w;
            }
        }
    }
#pragma unroll
    for (int off = 16; off < 64; off <<= 1) {
        acc.x += __shfl_xor(acc.x, off);
        acc.y += __shfl_xor(acc.y, off);
        acc.z += __shfl_xor(acc.z, off);
        acc.w += __shfl_xor(acc.w, off);
    }
    int deg = re - ro;
    float inv = 1.0f / (float)(deg > 0 ? deg : 1);
    if (lane < 16) {
        ((float4*)(meanout + (size_t)node * 64))[c4] =
            make_float4(acc.x * inv, acc.y * inv, acc.z * inv, acc.w * inv);
    }
}

// ---------- sage: xout = mean @ LW + lb + xin @ RW ----------
__global__ __launch_bounds__(256) void sage_kernel(const float* __restrict__ mean, const float* __restrict__ xin,
                            const float* __restrict__ lw, const float* __restrict__ lb,
                            const float* __restrict__ rw, float* __restrict__ xout, int N) {
    __shared__ __align__(16) float LW[64 * 64];
    __shared__ __align__(16) float RW[64 * 64];
    __shared__ float LB[64];
    int t = threadIdx.x;
    for (int i = t; i < 64 * 64; i += 256) { LW[i] = lw[i]; RW[i] = rw[i]; }
    if (t < 64) LB[t] = lb[t];
    __syncthreads();
    int row = blockIdx.x * 256 + t;
    if (row >= N) return;
    float acc[64];
#pragma unroll
    for (int j = 0; j < 64; j++) acc[j] = LB[j];
    const float4* mr = (const float4*)(mean + (size_t)row * 64);
    const float4* xr = (const float4*)(xin + (size_t)row * 64);
#pragma unroll
    for (int c = 0; c < 16; c++) {
        float4 xv = mr[c];
        float xs[4] = {xv.x, xv.y, xv.z, xv.w};
#pragma unroll
        for (int kk = 0; kk < 4; kk++) {
            int k = c * 4 + kk;
#pragma unroll
            for (int j4 = 0; j4 < 16; j4++) {
                float4 w = *(const float4*)&LW[k * 64 + j4 * 4];
                acc[j4 * 4 + 0] += xs[kk] * w.x;
                acc[j4 * 4 + 1] += xs[kk] * w.y;
                acc[j4 * 4 + 2] += xs[kk] * w.z;
                acc[j4 * 4 + 3] += xs[kk] * w.w;
            }
        }
    }
#pragma unroll
    for (int c = 0; c < 16; c++) {
        float4 xv = xr[c];
        float xs[4] = {xv.x, xv.y, xv.z, xv.w};
#pragma unroll
        for (int kk = 0; kk < 4; kk++) {
            int k = c * 4 + kk;
#pragma unroll
            for (int j4 = 0; j4 < 16; j4++) {
                float4 w = *(const float4*)&RW[k * 64 + j4 * 4];
                acc[j4 * 4 + 0] += xs[kk] * w.x;
                acc[j4 * 4 + 1] += xs[kk] * w.y;
                acc[j4 * 4 + 2] += xs[kk] * w.z;
                acc[j4 * 4 + 3] += xs[kk] * w.w;
            }
        }
    }
    float4* yr = (float4*)(xout + (size_t)row * 64);
#pragma unroll
    for (int c = 0; c < 16; c++)
        yr[c] = make_float4(acc[c * 4], acc[c * 4 + 1], acc[c * 4 + 2], acc[c * 4 + 3]);
}

// ---------- head: e0..e2, merge, gate, v; per-graph max of g ----------
__global__ __launch_bounds__(256) void head_kernel(const float* __restrict__ x0, const float* __restrict__ x1,
                            const float* __restrict__ x2, const int* __restrict__ batch,
                            const float* __restrict__ e0w, const float* __restrict__ e0b,
                            const float* __restrict__ e1w, const float* __restrict__ e1b,
                            const float* __restrict__ e2w, const float* __restrict__ e2b,
                            const float* __restrict__ mw, const float* __restrict__ mb,
                            const float* __restrict__ gw, const float* __restrict__ gbp,
                            const float* __restrict__ vw, const float* __restrict__ vb,
                            float* __restrict__ gout, float* __restrict__ vout,
                            unsigned* __restrict__ mkey, int N) {
    __shared__ __align__(16) float EW[3 * 64 * 32];
    __shared__ __align__(16) float MW[96 * 32];
    __shared__ __align__(16) float VW[32 * 32];
    __shared__ float EB[96], MB[32], GW[32], VB[32];
    __shared__ float GB;
    __shared__ unsigned smax[16];
    int t = threadIdx.x;
    for (int i = t; i < 2048; i += 256) { EW[i] = e0w[i]; EW[2048 + i] = e1w[i]; EW[4096 + i] = e2w[i]; }
    for (int i = t; i < 3072; i += 256) MW[i] = mw[i];
    for (int i = t; i < 1024; i += 256) VW[i] = vw[i];
    if (t < 32) { EB[t] = e0b[t]; EB[32 + t] = e1b[t]; EB[64 + t] = e2b[t];
                  MB[t] = mb[t]; GW[t] = gw[t]; VB[t] = vb[t]; }
    if (t == 0) GB = gbp[0];
    if (t < 16) smax[t] = 0u;
    __syncthreads();
    int node = blockIdx.x * 256 + t;
    if (node < N) {
        float xc[32];
#pragma unroll
        for (int j = 0; j < 32; j++) xc[j] = MB[j];
        const float* px[3] = {x0 + (size_t)node * 64, x1 + (size_t)node * 64, x2 + (size_t)node * 64};
        for (int h = 0; h < 3; h++) {
            float e[32];
#pragma unroll
            for (int j = 0; j < 32; j++) e[j] = EB[h * 32 + j];
            const float4* xr = (const float4*)px[h];
#pragma unroll
            for (int c = 0; c < 16; c++) {
                float4 xv = xr[c];
                float xs[4] = {xv.x, xv.y, xv.z, xv.w};
#pragma unroll
                for (int kk = 0; kk < 4; kk++) {
                    int k = c * 4 + kk;
#pragma unroll
                    for (int j4 = 0; j4 < 8; j4++) {
                        float4 w = *(const float4*)&EW[h * 2048 + k * 32 + j4 * 4];
                        e[j4 * 4 + 0] += xs[kk] * w.x;
                        e[j4 * 4 + 1] += xs[kk] * w.y;
                        e[j4 * 4 + 2] += xs[kk] * w.z;
                        e[j4 * 4 + 3] += xs[kk] * w.w;
                    }
                }
            }
#pragma unroll
            for (int j = 0; j < 32; j++) e[j] = fmaxf(e[j], 0.f);
#pragma unroll
            for (int i = 0; i < 32; i++) {
#pragma unroll
                for (int j4 = 0; j4 < 8; j4++) {
                    float4 w = *(const float4*)&MW[(h * 32 + i) * 32 + j4 * 4];
                    xc[j4 * 4 + 0] += e[i] * w.x;
                    xc[j4 * 4 + 1] += e[i] * w.y;
                    xc[j4 * 4 + 2] += e[i] * w.z;
                    xc[j4 * 4 + 3] += e[i] * w.w;
                }
            }
        }
#pragma unroll
        for (int j = 0; j < 32; j++) xc[j] = fmaxf(xc[j], 0.f);
        float g = GB;
#pragma unroll
        for (int i = 0; i < 32; i++) g += xc[i] * GW[i];
        float vv[32];
#pragma unroll
        for (int j = 0; j < 32; j++) vv[j] = VB[j];
#pragma unroll
        for (int i = 0; i < 32; i++) {
#pragma unroll
            for (int j4 = 0; j4 < 8; j4++) {
                float4 w = *(const float4*)&VW[i * 32 + j4 * 4];
                vv[j4 * 4 + 0] += xc[i] * w.x;
                vv[j4 * 4 + 1] += xc[i] * w.y;
                vv[j4 * 4 + 2] += xc[i] * w.z;
                vv[j4 * 4 + 3] += xc[i] * w.w;
            }
        }
        gout[node] = g;
        float4* vr = (float4*)(vout + (size_t)node * 32);
#pragma unroll
        for (int c = 0; c < 8; c++)
            vr[c] = make_float4(vv[c * 4], vv[c * 4 + 1], vv[c * 4 + 2], vv[c * 4 + 3]);
        int b = batch[node];
        atomicMax(&smax[b], fkey(g));
    }
    __syncthreads();
    if (t < 16) atomicMax(&mkey[t], smax[t]);
}

// ---------- pool: d = seg_sum(e), num = seg_sum(e*v) ----------
__global__ __launch_bounds__(256) void pool_kernel(const float* __restrict__ g, const float* __restrict__ v,
                            const int* __restrict__ batch, const unsigned* __restrict__ mkey,
                            float* __restrict__ dsum, float* __restrict__ pooled, int N) {
    __shared__ float sd[16];
    __shared__ float sp[16 * 32];
    __shared__ float sm[16];
    int t = threadIdx.x;
    if (t < 16) { sd[t] = 0.f; sm[t] = funkey(mkey[t]); }
    for (int i = t; i < 512; i += 256) sp[i] = 0.f;
    __syncthreads();
    int node = blockIdx.x * 256 + t;
    if (node < N) {
        int b = batch[node];
        float e = __expf(g[node] - sm[b]);
        atomicAdd(&sd[b], e);
        const float4* vr = (const float4*)(v + (size_t)node * 32);
#pragma unroll
        for (int c = 0; c < 8; c++) {
            float4 vv = vr[c];
            atomicAdd(&sp[b * 32 + c * 4 + 0], e * vv.x);
            atomicAdd(&sp[b * 32 + c * 4 + 1], e * vv.y);
            atomicAdd(&sp[b * 32 + c * 4 + 2], e * vv.z);
            atomicAdd(&sp[b * 32 + c * 4 + 3], e * vv.w);
        }
    }
    __syncthreads();
    if (t < 16) atomicAdd(&dsum[t], sd[t]);
    for (int i = t; i < 512; i += 256) atomicAdd(&pooled[i], sp[i]);
}

// ---------- final: logits + softmax ----------
__global__ __launch_bounds__(64) void final_kernel(const float* __restrict__ dsum, const float* __restrict__ pooled,
                             const float* __restrict__ ow, const float* __restrict__ ob,
                             float* __restrict__ out) {
    int t = threadIdx.x;
    if (t >= 16) return;
    float d = dsum[t];
    float l0 = ob[0], l1 = ob[1];
    for (int i = 0; i < 32; i++) {
        float p = pooled[t * 32 + i] / d;
        l0 += p * ow[i * 2 + 0];
        l1 += p * ow[i * 2 + 1];
    }
    float m = fmaxf(l0, l1);
    float e0 = __expf(l0 - m), e1 = __expf(l1 - m);
    float s = e0 + e1;
    out[t * 2 + 0] = e0 / s;
    out[t * 2 + 1] = e1 / s;
    out[32 + t * 2 + 0] = l0;
    out[32 + t * 2 + 1] = l1;
}

extern "C" void kernel_launch(void* const* d_in, const int* in_sizes, int n_in,
                              void* d_out, int out_size, void* d_ws, size_t ws_size,
                              hipStream_t stream) {
    const float* x       = (const float*)d_in[0];
    const int*   ei      = (const int*)d_in[1];
    const int*   batch   = (const int*)d_in[2];
    const float* lin0_w  = (const float*)d_in[3];
    const float* lin0_b  = (const float*)d_in[4];
    const float* s1_lw   = (const float*)d_in[5];
    const float* s1_lb   = (const float*)d_in[6];
    const float* s1_rw   = (const float*)d_in[7];
    const float* s2_lw   = (const float*)d_in[8];
    const float* s2_lb   = (const float*)d_in[9];
    const float* s2_rw   = (const float*)d_in[10];
    const float* e0w     = (const float*)d_in[11];
    const float* e0b     = (const float*)d_in[12];
    const float* e1w     = (const float*)d_in[13];
    const float* e1b     = (const float*)d_in[14];
    const float* e2w     = (const float*)d_in[15];
    const float* e2b     = (const float*)d_in[16];
    const float* mw      = (const float*)d_in[17];
    const float* mb      = (const float*)d_in[18];
    const float* gw      = (const float*)d_in[19];
    const float* gb      = (const float*)d_in[20];
    const float* vw      = (const float*)d_in[21];
    const float* vb      = (const float*)d_in[22];
    const float* ow      = (const float*)d_in[23];
    const float* ob      = (const float*)d_in[24];
    float* out = (float*)d_out;

    const int N = N_NODES, E = N_EDGES;
    const int* src = ei;
    const int* dst = ei + E;

    // workspace carve
    char* p = (char*)d_ws;
    auto carve = [&](size_t bytes) { char* r = p; p += (bytes + 255) & ~(size_t)255; return (void*)r; };
    float* x0      = (float*)carve((size_t)N * 64 * 4);
    float* x1      = (float*)carve((size_t)N * 64 * 4);
    float* x2      = (float*)carve((size_t)N * 64 * 4);
    float* meanb   = (float*)carve((size_t)N * 64 * 4);
    float* vbuf    = (float*)carve((size_t)N * 32 * 4);
    float* gbuf    = (float*)carve((size_t)N * 4);
    int*   csr     = (int*)carve((size_t)E * 4);
    int*   pos     = (int*)carve((size_t)E * 4);
    int*   deg     = (int*)carve((size_t)N * 4);
    int*   rowstart= (int*)carve((size_t)(N + 1) * 4);
    int*   blocksum= (int*)carve(64 * 4);
    int*   blockoff= (int*)carve(64 * 4);
    unsigned* mkey = (unsigned*)carve(16 * 4);
    float* dsum    = (float*)carve(16 * 4);
    float* pooled  = (float*)carve(16 * 32 * 4);

    hipMemsetAsync(deg, 0, (size_t)N * 4, stream);
    hipMemsetAsync(mkey, 0, 16 * 4, stream);
    hipMemsetAsync(dsum, 0, 16 * 4, stream);
    hipMemsetAsync(pooled, 0, 16 * 32 * 4, stream);

    const int E4 = E / 4;                 // E divisible by 4
    int e4bl = (E4 + 255) / 256;
    int nbl = (N + 255) / 256;
    int abl = (N + 3) / 4;
    int sbl = (N + SCAN_CHUNK - 1) / SCAN_CHUNK;   // 49

    count_kernel<<<e4bl, 256, 0, stream>>>(dst, deg, pos, E4);
    scan_partial<<<sbl, 256, 0, stream>>>(deg, blocksum, N);
    scan_blocksums<<<1, 64, 0, stream>>>(blocksum, blockoff, rowstart, sbl, N);
    scan_scatter<<<sbl, 256, 0, stream>>>(deg, blockoff, rowstart, N);
    fill_kernel<<<e4bl, 256, 0, stream>>>(src, dst, pos, rowstart, csr, E4);

    lin0_kernel<<<nbl, 256, 0, stream>>>(x, lin0_w, lin0_b, x0, N);

    agg_kernel<<<abl, 256, 0, stream>>>(x0, rowstart, csr, meanb, N);
    sage_kernel<<<nbl, 256, 0, stream>>>(meanb, x0, s1_lw, s1_lb, s1_rw, x1, N);

    agg_kernel<<<abl, 256, 0, stream>>>(x1, rowstart, csr, meanb, N);
    sage_kernel<<<nbl, 256, 0, stream>>>(meanb, x1, s2_lw, s2_lb, s2_rw, x2, N);

    head_kernel<<<nbl, 256, 0, stream>>>(x0, x1, x2, batch,
                                         e0w, e0b, e1w, e1b, e2w, e2b,
                                         mw, mb, gw, gb, vw, vb,
                                         gbuf, vbuf, mkey, N);

    pool_kernel<<<nbl, 256, 0, stream>>>(gbuf, vbuf, batch, mkey, dsum, pooled, N);

    final_kernel<<<1, 64, 0, stream>>>(dsum, pooled, ow, ob, out);
}